// Round 20
// baseline (58.116 us; speedup 1.0000x reference)
//
#include <hip/hip_runtime.h>
#include <hip/hip_fp16.h>
#include <math.h>

#define PATCH 41
#define PSIZE (PATCH * PATCH)   // 1681
#define NUM_ANG 8
#define KS 16
#define STRIDE 10
#define PAD 4
#define DESC 128
#define CLIPVAL 0.2f

#define NQ4 (PATCH * 10)         // 410 uniform quads (x = 0..39)
#define CST 33                   // colsum row stride (floats, ODD)
#define RS 56                    // s_bins row stride in halves (16B-mult, 2-way banks)
#define NROWS 336                // 21 tiles x 16 rows (328 real = 8y+a, 8 pad)
#define BINS_HALVES (NROWS * RS + 64)   // 18880; +64 guard for K-step-2 tail reads

struct F4 { float x, y, z, w; };

typedef _Float16 v8h __attribute__((ext_vector_type(8)));
typedef float    v4f __attribute__((ext_vector_type(4)));

// ---- DPP-based wave64 sum (VALU pipe only, no LDS, no barriers) ----
template <int CTRL>
__device__ __forceinline__ float dpp_add(float v) {
    const int s = __builtin_amdgcn_update_dpp(
        0, __builtin_bit_cast(int, v), CTRL, 0xF, 0xF, true);
    return v + __builtin_bit_cast(float, s);
}
__device__ __forceinline__ float wave_sum_dpp(float v) {
    v = dpp_add<0x111>(v);   // row_shr:1
    v = dpp_add<0x112>(v);   // row_shr:2
    v = dpp_add<0x114>(v);   // row_shr:4
    v = dpp_add<0x118>(v);   // row_shr:8
    v = dpp_add<0x142>(v);   // row_bcast:15
    v = dpp_add<0x143>(v);   // row_bcast:31 -> lane 63 = total
    return __builtin_bit_cast(float,
        __builtin_amdgcn_readlane(__builtin_bit_cast(int, v), 63));
}

// x-pool weight: tap x for window j (0 outside window, 0 for x>=41 = conv pad)
__device__ __forceinline__ float wxw(int x, int j) {
    if (j >= 4 || x > 40) return 0.0f;
    const int dd = x - (j * STRIDE - PAD);
    if (dd < 0 || dd > 15) return 0.0f;
    const int m = dd < 8 ? dd : 15 - dd;
    return ((float)m + 0.5f) * 0.125f;
}

// per-pixel: UN-HALVED gradients -> orientation -> two b16 writes into rows 8y+a
__device__ __forceinline__ void bin_px(__half* px_base, float gx2, float gy2, float gkv) {
    float g2 = fmaf(gx2, gx2, 4e-10f);
    g2 = fmaf(gy2, gy2, g2);
    const float mag = __builtin_amdgcn_sqrtf(g2) * (gkv * 512.0f);

    const float gxp = gx2 + 2e-10f;
    const float ax = fabsf(gxp), ay = fabsf(gy2);
    const float mx = fmaxf(ax, ay);
    const float mn = fminf(ax, ay);
    const float t  = mn * __builtin_amdgcn_rcpf(fmaxf(mx, 1e-20f));
    const float s  = t * t;
    float r = t * fmaf(s, fmaf(s, fmaf(s, fmaf(s, 0.02652810f, -0.10839420f),
                                       0.22936229f), -0.42055650f), 1.27306897f);
    r = (ay > ax)     ? 2.0f - r : r;
    r = (gxp < 0.0f)  ? 4.0f - r : r;
    r = (gy2 < 0.0f)  ? 8.0f - r : r;      // octant units in [0, 8]

    const float bf = floorf(r);
    const float f  = r - bf;
    const int b0 = ((int)bf) & (NUM_ANG - 1);
    const int b1 = (b0 + 1) & (NUM_ANG - 1);
    px_base[b0 * RS] = __float2half((1.0f - f) * mag);
    px_base[b1 * RS] = __float2half(f * mag);
}

__global__ __launch_bounds__(512) void sift_desc_kernel(
    const float* __restrict__ input,
    const float* __restrict__ gk,
    float* __restrict__ out)
{
    __shared__ __align__(16) __half s_bins[BINS_HALVES];  // 37760 B, row r=8y+a, col x
    __shared__ float s_cs[PATCH * CST];                   // 5412 B

    const int tid = threadIdx.x;
    const int b   = blockIdx.x;
    const float* in_p = input + (size_t)b * PSIZE;

    const float w1r[KS] = {0.0625f, 0.1875f, 0.3125f, 0.4375f,
                           0.5625f, 0.6875f, 0.8125f, 0.9375f,
                           0.9375f, 0.8125f, 0.6875f, 0.5625f,
                           0.4375f, 0.3125f, 0.1875f, 0.0625f};

    // ---- phase 0: zero bins (incl. pad rows + guard) ----
    {
        float4* z = (float4*)s_bins;
        const float4 zero = make_float4(0.f, 0.f, 0.f, 0.f);
        for (int i = tid; i < BINS_HALVES / 8; i += 512) z[i] = zero;
    }
    __syncthreads();

    // ---- phase 1 (flat): one quad/thread; tail column on wave-7 threads ----
    if (tid < NQ4) {
        const int y  = tid / 10;
        const int xq = (tid - y * 10) * 4;
        const int ym = max(y - 1, 0), yp = min(y + 1, PATCH - 1);
        const float* cr = in_p + y  * PATCH;
        const float* ur = in_p + ym * PATCH;
        const float* dr = in_p + yp * PATCH;
        const float* gr = gk + y * PATCH;
        __half* pb = s_bins + y * (8 * RS) + xq;

        const F4 c = *(const F4*)(cr + xq);
        const F4 u = *(const F4*)(ur + xq);
        const F4 d = *(const F4*)(dr + xq);
        const F4 g = *(const F4*)(gr + xq);
        const float L = cr[max(xq - 1, 0)];
        const float R = cr[xq + 4];

        bin_px(pb,     (c.y - L),   (d.x - u.x), g.x);
        bin_px(pb + 1, (c.z - c.x), (d.y - u.y), g.y);
        bin_px(pb + 2, (c.w - c.y), (d.z - u.z), g.z);
        bin_px(pb + 3, (R  - c.z),  (d.w - u.w), g.w);
    } else if (tid >= 448 && tid < 448 + PATCH) {   // tail column x = 40
        const int y = tid - 448;
        const int ym = max(y - 1, 0), yp = min(y + 1, PATCH - 1);
        const float* cr = in_p + y * PATCH;
        bin_px(s_bins + y * (8 * RS) + 40,
               (cr[40] - cr[39]),
               (in_p[yp * PATCH + 40] - in_p[ym * PATCH + 40]),
               gk[y * PATCH + 40]);
    }
    __syncthreads();

    // ---- phase 2a: x-pool as MFMA. A = bins rows (16/tile), B = weights ----
    // A-frag: row = lane&15, k = (lane>>4)*8 + e (contiguous 16B per lane)
    // D:      col = lane&15 (=j), row = (lane>>4)*4 + reg
    {
        const int lane = tid & 63;
        const int wid  = tid >> 6;
        const int g  = lane >> 4;
        const int lo = lane & 15;

        v8h b1, b2;
        #pragma unroll
        for (int e = 0; e < 8; ++e) {
            const int k = g * 8 + e;
            b1[e] = (_Float16)wxw(k, lo);        // K-step 1: x = k
            b2[e] = (_Float16)wxw(32 + k, lo);   // K-step 2: x = 32+k
        }

        for (int t = wid; t < 21; t += 8) {
            const int r0 = t * 16;
            const __half* ap = s_bins + (r0 + lo) * RS + g * 8;
            const v8h a1 = *(const v8h*)ap;
            const v8h a2 = *(const v8h*)(ap + 32);

            v4f acc = {0.f, 0.f, 0.f, 0.f};
            acc = __builtin_amdgcn_mfma_f32_16x16x32_f16(a1, b1, acc, 0, 0, 0);
            acc = __builtin_amdgcn_mfma_f32_16x16x32_f16(a2, b2, acc, 0, 0, 0);

            if (lo < 4) {                        // only j<4 columns are real
                #pragma unroll
                for (int q = 0; q < 4; ++q) {
                    const int r = r0 + g * 4 + q;
                    if (r < NUM_ANG * PATCH) {   // skip pad rows
                        s_cs[(r >> 3) * CST + lo * 8 + (r & 7)] = acc[q];
                    }
                }
            }
        }
    }
    __syncthreads();

    // ---- phases 2b + norm: single wave, DPP reductions ----
    if (tid < 64) {
        const int lane = tid;
        float v0 = 0.0f, v1 = 0.0f;
        int a0i = 0, jj0 = 0, ii0 = 0, a1i = 0, jj1 = 0, ii1 = 0;
        #pragma unroll
        for (int h = 0; h < 2; ++h) {
            const int item = lane + h * 64;
            const int a  = item & 7;
            const int jj = (item >> 3) & 3;
            const int ii = item >> 5;
            const int py0 = ii * STRIDE - PAD;
            float s = 0.0f;
            #pragma unroll
            for (int dy = 0; dy < KS; ++dy) {
                const int py  = py0 + dy;
                const int pyc = min(max(py, 0), PATCH - 1);
                const float wv = (py == pyc) ? w1r[dy] : 0.0f;
                s = fmaf(wv, s_cs[pyc * CST + jj * 8 + a], s);
            }
            if (h == 0) { v0 = s; a0i = a; jj0 = jj; ii0 = ii; }
            else        { v1 = s; a1i = a; jj1 = jj; ii1 = ii; }
        }

        const float ss1 = wave_sum_dpp(fmaf(v0, v0, v1 * v1));
        const float inv1 = 1.0f / fmaxf(sqrtf(ss1), 1e-12f);
        const float c0 = fminf(fmaxf(v0 * inv1, 0.0f), CLIPVAL);
        const float c1 = fminf(fmaxf(v1 * inv1, 0.0f), CLIPVAL);

        const float ss2 = wave_sum_dpp(fmaf(c0, c0, c1 * c1));
        const float inv2 = 1.0f / fmaxf(sqrtf(ss2), 1e-12f);
        const float b0 = c0 * inv2;
        const float b1 = c1 * inv2;

        const float l1 = wave_sum_dpp(fabsf(b0) + fabsf(b1));
        const float invl = 1.0f / fmaxf(l1, 1e-12f);
        const float o0 = sqrtf(fmaf(b0, invl, 1e-10f));
        const float o1 = sqrtf(fmaf(b1, invl, 1e-10f));

        // reference layout: desc[ang*16 + i*4 + j]
        out[(size_t)b * DESC + (a0i * 16 + ii0 * 4 + jj0)] = o0;
        out[(size_t)b * DESC + (a1i * 16 + ii1 * 4 + jj1)] = o1;
    }
}

extern "C" void kernel_launch(void* const* d_in, const int* in_sizes, int n_in,
                              void* d_out, int out_size, void* d_ws, size_t ws_size,
                              hipStream_t stream) {
    const float* input = (const float*)d_in[0];
    const float* gk    = (const float*)d_in[1];
    float* out         = (float*)d_out;

    const int B = in_sizes[0] / PSIZE;
    if (B <= 0) return;
    sift_desc_kernel<<<dim3(B), dim3(512), 0, stream>>>(input, gk, out);
}

// Round 21
// 34.556 us; speedup vs baseline: 1.6818x; 1.6818x over previous
//
#include <hip/hip_runtime.h>
#include <hip/hip_fp16.h>
#include <math.h>

#define PATCH 41
#define PSIZE (PATCH * PATCH)   // 1681
#define NUM_ANG 8
#define KS 16
#define STRIDE 10
#define PAD 4
#define DESC 128
#define CLIPVAL 0.2f

#define NQ4 (PATCH * 10)         // 410 uniform quads (x = 0..39)
#define CST 33                   // colsum row stride (floats, ODD -> bank spread)
#define ROWH (PATCH * 8)         // s_bins row stride in halves

struct F4 { float x, y, z, w; };

typedef _Float16 h2t __attribute__((ext_vector_type(2)));

// ---- DPP-based wave64 sum (VALU pipe only, no LDS, no barriers) ----
template <int CTRL>
__device__ __forceinline__ float dpp_add(float v) {
    const int s = __builtin_amdgcn_update_dpp(
        0, __builtin_bit_cast(int, v), CTRL, 0xF, 0xF, true);
    return v + __builtin_bit_cast(float, s);
}
__device__ __forceinline__ float wave_sum_dpp(float v) {
    v = dpp_add<0x111>(v);   // row_shr:1
    v = dpp_add<0x112>(v);   // row_shr:2
    v = dpp_add<0x114>(v);   // row_shr:4
    v = dpp_add<0x118>(v);   // row_shr:8
    v = dpp_add<0x142>(v);   // row_bcast:15
    v = dpp_add<0x143>(v);   // row_bcast:31 -> lane 63 = total
    return __builtin_bit_cast(float,
        __builtin_amdgcn_readlane(__builtin_bit_cast(int, v), 63));
}

// per-pixel: UN-HALVED gradients -> orientation -> two b16 slot writes
__device__ __forceinline__ void bin_px(__half* sb, int pix, float gx2, float gy2, float gkv) {
    float g2 = fmaf(gx2, gx2, 4e-10f);
    g2 = fmaf(gy2, gy2, g2);
    const float mag = __builtin_amdgcn_sqrtf(g2) * (gkv * 512.0f);

    const float gxp = gx2 + 2e-10f;
    const float ax = fabsf(gxp), ay = fabsf(gy2);
    const float mx = fmaxf(ax, ay);
    const float mn = fminf(ax, ay);
    const float t  = mn * __builtin_amdgcn_rcpf(fmaxf(mx, 1e-20f));
    const float s  = t * t;
    float r = t * fmaf(s, fmaf(s, fmaf(s, fmaf(s, 0.02652810f, -0.10839420f),
                                       0.22936229f), -0.42055650f), 1.27306897f);
    r = (ay > ax)     ? 2.0f - r : r;
    r = (gxp < 0.0f)  ? 4.0f - r : r;
    r = (gy2 < 0.0f)  ? 8.0f - r : r;      // octant units in [0, 8]

    const int bi = (int)r;                 // trunc == floor for r >= 0
    const float f = r - (float)bi;
    const int b0 = bi & (NUM_ANG - 1);
    const int b1 = (b0 + 1) & (NUM_ANG - 1);
    __half* slot = sb + pix * NUM_ANG;
    slot[b0] = __float2half((1.0f - f) * mag);
    slot[b1] = __float2half(f * mag);
}

__global__ __launch_bounds__(512) void sift_desc_kernel(
    const float* __restrict__ input,
    const float* __restrict__ gk,
    float* __restrict__ out)
{
    __shared__ __align__(16) __half s_bins[PSIZE * NUM_ANG];  // 26896 B, [pix][a]
    __shared__ float s_cs[PATCH * CST];                       // 5412 B

    const int tid = threadIdx.x;
    const int b   = blockIdx.x;
    const float* in_p = input + (size_t)b * PSIZE;

    const float w1r[KS] = {0.0625f, 0.1875f, 0.3125f, 0.4375f,
                           0.5625f, 0.6875f, 0.8125f, 0.9375f,
                           0.9375f, 0.8125f, 0.6875f, 0.5625f,
                           0.4375f, 0.3125f, 0.1875f, 0.0625f};

    // ---- phase 0: zero the bins (1681 x 16B) ----
    {
        float4* z = (float4*)s_bins;
        const float4 zero = make_float4(0.f, 0.f, 0.f, 0.f);
        for (int i = tid; i < PSIZE; i += 512) z[i] = zero;
    }
    __syncthreads();

    // ---- phase 1 (flat): one quad/thread; tail column on wave-7 threads ----
    if (tid < NQ4) {
        const int y  = tid / 10;
        const int xq = (tid - y * 10) * 4;
        const int ym = max(y - 1, 0), yp = min(y + 1, PATCH - 1);
        const float* cr = in_p + y  * PATCH;
        const float* ur = in_p + ym * PATCH;
        const float* dr = in_p + yp * PATCH;
        const float* gr = gk + y * PATCH;
        const int pix = y * PATCH + xq;

        const F4 c = *(const F4*)(cr + xq);
        const F4 u = *(const F4*)(ur + xq);
        const F4 d = *(const F4*)(dr + xq);
        const F4 g = *(const F4*)(gr + xq);
        const float L = cr[max(xq - 1, 0)];
        const float R = cr[xq + 4];

        bin_px(s_bins, pix,     (c.y - L),   (d.x - u.x), g.x);
        bin_px(s_bins, pix + 1, (c.z - c.x), (d.y - u.y), g.y);
        bin_px(s_bins, pix + 2, (c.w - c.y), (d.z - u.z), g.z);
        bin_px(s_bins, pix + 3, (R  - c.z),  (d.w - u.w), g.w);
    } else if (tid >= 448 && tid < 448 + PATCH) {   // tail column x = 40
        const int y = tid - 448;
        const int ym = max(y - 1, 0), yp = min(y + 1, PATCH - 1);
        const float* cr = in_p + y * PATCH;
        bin_px(s_bins, y * PATCH + 40,
               (cr[40] - cr[39]),
               (in_p[yp * PATCH + 40] - in_p[ym * PATCH + 40]),
               gk[y * PATCH + 40]);
    }
    __syncthreads();

    // ---- phase 2a: thread = (angle-pair k, row y); f16 pk_fma accumulation ----
    if (tid < PATCH * 4) {
        const int k = tid & 3;        // angle pair: angles 2k, 2k+1
        const int y = tid >> 2;
        const __half* sb = s_bins + y * ROWH + k * 2;

        h2t acc[4];                   // one half2 accumulator per window j
        #pragma unroll
        for (int i = 0; i < 4; ++i) acc[i] = (h2t){(_Float16)0.0f, (_Float16)0.0f};

        #pragma unroll
        for (int x = 0; x < PATCH; ++x) {
            const h2t h = *(const h2t*)(sb + x * NUM_ANG);
            #pragma unroll
            for (int j = 0; j < 4; ++j) {
                const int dd = x - (j * STRIDE - PAD);
                if (dd >= 0 && dd < KS) {           // compile-time after unroll
                    const float wf = ((dd < 8 ? dd : 15 - dd) + 0.5f) * 0.125f;
                    const _Float16 w = (_Float16)wf; // exact in f16 (16ths)
                    acc[j] = __builtin_elementwise_fma((h2t){w, w}, h, acc[j]);
                }
            }
        }
        float* cs = s_cs + y * CST + k * 2;
        #pragma unroll
        for (int j = 0; j < 4; ++j) {
            cs[j * 8]     = (float)acc[j][0];
            cs[j * 8 + 1] = (float)acc[j][1];
        }
    }
    __syncthreads();

    // ---- phases 2b + norm: single wave, DPP reductions ----
    if (tid < 64) {
        const int lane = tid;
        float v0 = 0.0f, v1 = 0.0f;
        int a0i = 0, jj0 = 0, ii0 = 0, a1i = 0, jj1 = 0, ii1 = 0;
        #pragma unroll
        for (int h = 0; h < 2; ++h) {
            const int item = lane + h * 64;
            const int a  = item & 7;
            const int jj = (item >> 3) & 3;
            const int ii = item >> 5;
            const int py0 = ii * STRIDE - PAD;
            float s = 0.0f;
            #pragma unroll
            for (int dy = 0; dy < KS; ++dy) {
                const int py  = py0 + dy;
                const int pyc = min(max(py, 0), PATCH - 1);
                const float wv = (py == pyc) ? w1r[dy] : 0.0f;
                s = fmaf(wv, s_cs[pyc * CST + jj * 8 + a], s);
            }
            if (h == 0) { v0 = s; a0i = a; jj0 = jj; ii0 = ii; }
            else        { v1 = s; a1i = a; jj1 = jj; ii1 = ii; }
        }

        const float ss1 = wave_sum_dpp(fmaf(v0, v0, v1 * v1));
        const float inv1 = 1.0f / fmaxf(sqrtf(ss1), 1e-12f);
        const float c0 = fminf(fmaxf(v0 * inv1, 0.0f), CLIPVAL);
        const float c1 = fminf(fmaxf(v1 * inv1, 0.0f), CLIPVAL);

        const float ss2 = wave_sum_dpp(fmaf(c0, c0, c1 * c1));
        const float inv2 = 1.0f / fmaxf(sqrtf(ss2), 1e-12f);
        const float b0 = c0 * inv2;
        const float b1 = c1 * inv2;

        const float l1 = wave_sum_dpp(fabsf(b0) + fabsf(b1));
        const float invl = 1.0f / fmaxf(l1, 1e-12f);
        const float o0 = sqrtf(fmaf(b0, invl, 1e-10f));
        const float o1 = sqrtf(fmaf(b1, invl, 1e-10f));

        // reference layout: desc[ang*16 + i*4 + j]
        out[(size_t)b * DESC + (a0i * 16 + ii0 * 4 + jj0)] = o0;
        out[(size_t)b * DESC + (a1i * 16 + ii1 * 4 + jj1)] = o1;
    }
}

extern "C" void kernel_launch(void* const* d_in, const int* in_sizes, int n_in,
                              void* d_out, int out_size, void* d_ws, size_t ws_size,
                              hipStream_t stream) {
    const float* input = (const float*)d_in[0];
    const float* gk    = (const float*)d_in[1];
    float* out         = (float*)d_out;

    const int B = in_sizes[0] / PSIZE;
    if (B <= 0) return;
    sift_desc_kernel<<<dim3(B), dim3(512), 0, stream>>>(input, gk, out);
}